// Round 3
// baseline (947.141 us; speedup 1.0000x reference)
//
#include <hip/hip_runtime.h>

#define B_SZ 32
#define L 4096
#define H 512
#define P 384
#define V 32
#define OUT_LEN 16
#define NSC 12        // super-chunks
#define SCLEN 340     // 4 interleaved streams x 85 steps
#define NSTEP 85
#define T0 4080       // NSC*SCLEN; 16-step tail = the 16 output states

// ---- ws layout (float offsets) ----
#define OFF_DBL   0         // [P][6] doubles (lbr,lbi,-,-,cr,ci)
#define OFF_LBF4  4608      // [P][2] float Lambda_bar^4
#define OFF_WPOW  5376      // [NSC][P][2] doubles: W^(NSC-1-c), W = Lbar^340
#define OFF_M     23808     // [V][P][2] UNSCALED dot table M0
#define OFF_CT    48384     // [P][2][H] transposed C
#define OFF_XP    441600    // [B][P][NSC][2] slotted scan partials (no atomics)
#define OFF_FLAGS 736512    // 16 ints: grid-barrier counters (zeroed by memset)
#define OFF_YT    736528    // [512 r][512 h], r = b*16+l
#define OFF_HP    998672    // [4][512][512] fc1 k-split partials
// end = 2047248 floats = 8.2 MB

#define NBLK 768

// grid-wide barrier. All 768 blocks co-resident by capacity: 48KB LDS ->
// exactly 3 blocks/CU (144<=160KB), launch_bounds(256,3) caps VGPR<=168 so
// registers can't lower occupancy, grid = 3 * 256 CUs. Regular launch ->
// graph-capture-safe (cooperative launch was not).
// Fences: EVERY thread executes release (drain stores + wb XCD L2) before
// the block arrives, and acquire (inv L1/L2) after the grid count completes.
__device__ __forceinline__ void gbar(int* flag) {
    __threadfence();   // ALL threads: release
    __syncthreads();   // arrive only after every wave's fence
    if (threadIdx.x == 0) {
        __hip_atomic_fetch_add(flag, 1, __ATOMIC_RELEASE, __HIP_MEMORY_SCOPE_AGENT);
        while (__hip_atomic_load(flag, __ATOMIC_ACQUIRE,
                                 __HIP_MEMORY_SCOPE_AGENT) < NBLK)
            __builtin_amdgcn_s_sleep(2);
    }
    __syncthreads();
    __threadfence();   // ALL threads: acquire
}

__global__ __launch_bounds__(256, 3) void k_all(
    const int* __restrict__ tokens, const float* __restrict__ embed,
    const float* __restrict__ Lre, const float* __restrict__ Lim,
    const float* __restrict__ Bre, const float* __restrict__ Bim,
    const float* __restrict__ Cre, const float* __restrict__ Cim,
    const float* __restrict__ D, const float* __restrict__ log_step,
    const float* __restrict__ W1, const float* __restrict__ b1,
    const float* __restrict__ W2, const float* __restrict__ b2,
    float* __restrict__ ws, float* __restrict__ out)
{
    __shared__ __align__(16) char smem[49152];   // 48KB, overlaid per phase
    int bx = blockIdx.x, tid = threadIdx.x;
    int* flags = (int*)(ws + OFF_FLAGS);

    // ================= P0: prep (original k_prep)
    if (bx < 2) {
        int p = bx * 256 + tid;
        if (p < P) {
            double dstep = exp((double)log_step[p]);
            double are = (double)Lre[p] * dstep, aim = (double)Lim[p] * dstep;
            double mag = exp(are);
            double lbr = mag * cos(aim), lbi = mag * sin(aim);
            double lre = (double)Lre[p], lim = (double)Lim[p];
            double nr = lbr - 1.0, ni = lbi;
            double den = lre * lre + lim * lim;
            double cr = (nr * lre + ni * lim) / den, ci = (ni * lre - nr * lim) / den;
            double* d = (double*)ws + p * 6;
            d[0] = lbr; d[1] = lbi; d[2] = 0.0; d[3] = 0.0; d[4] = cr; d[5] = ci;
            double m4 = exp(4.0 * are), a4 = 4.0 * aim;
            ws[OFF_LBF4 + 2 * p]     = (float)(m4 * cos(a4));
            ws[OFF_LBF4 + 2 * p + 1] = (float)(m4 * sin(a4));
            double wmag = exp((double)SCLEN * are);
            double wang = (double)SCLEN * aim;
            double wr = wmag * cos(wang), wi = wmag * sin(wang);
            double* wpow = (double*)(ws + OFF_WPOW);
            double awr = 1.0, awi = 0.0;
            for (int c = NSC - 1; c >= 0; --c) {
                wpow[(c * P + p) * 2]     = awr;
                wpow[(c * P + p) * 2 + 1] = awi;
                double t = awr * wr - awi * wi;
                awi = awr * wi + awi * wr;
                awr = t;
            }
        }
    } else if (bx < 194) {
        float (*sre)[33] = (float(*)[33])smem;
        float (*sim)[33] = (float(*)[33])(smem + 32 * 33 * 4);
        int bxx = bx - 2;
        int tp = bxx >> 4, th = bxx & 15;        // 12 p-tiles x 16 h-tiles
        int col = tid & 31, r0 = tid >> 5;
        #pragma unroll
        for (int it = 0; it < 4; ++it) {
            int row = r0 + 8 * it;
            int h = th * 32 + row, p = tp * 32 + col;
            sre[col][row] = Cre[h * P + p];
            sim[col][row] = Cim[h * P + p];
        }
        __syncthreads();
        #pragma unroll
        for (int it = 0; it < 4; ++it) {
            int pl = r0 + 8 * it;
            int p = tp * 32 + pl, h = th * 32 + col;
            ws[OFF_CT + (2 * p) * H + h]     = sre[pl][col];
            ws[OFF_CT + (2 * p + 1) * H + h] = sim[pl][col];
        }
    }
    if (bx < 384) {   // M0: 1536 wave-units
        int w = bx * 4 + (tid >> 6);
        if (w < 1536) {
            int v0 = (w & 3) * 8, p = w >> 2;
            int lane = tid & 63;
            const float4* brp = (const float4*)(Bre + p * H);
            const float4* bip = (const float4*)(Bim + p * H);
            float4 br0 = brp[lane], br1 = brp[lane + 64];
            float4 bi0 = bip[lane], bi1 = bip[lane + 64];
            #pragma unroll
            for (int vv = 0; vv < 8; ++vv) {
                const float4* evp = (const float4*)(embed + (v0 + vv) * H);
                float4 e0 = evp[lane], e1 = evp[lane + 64];
                float dr = br0.x * e0.x;
                dr = fmaf(br0.y, e0.y, dr); dr = fmaf(br0.z, e0.z, dr);
                dr = fmaf(br0.w, e0.w, dr); dr = fmaf(br1.x, e1.x, dr);
                dr = fmaf(br1.y, e1.y, dr); dr = fmaf(br1.z, e1.z, dr);
                dr = fmaf(br1.w, e1.w, dr);
                float di = bi0.x * e0.x;
                di = fmaf(bi0.y, e0.y, di); di = fmaf(bi0.z, e0.z, di);
                di = fmaf(bi0.w, e0.w, di); di = fmaf(bi1.x, e1.x, di);
                di = fmaf(bi1.y, e1.y, di); di = fmaf(bi1.z, e1.z, di);
                di = fmaf(bi1.w, e1.w, di);
                #pragma unroll
                for (int off = 32; off; off >>= 1) {
                    dr += __shfl_down(dr, off);
                    di += __shfl_down(di, off);
                }
                if (lane == 0) {
                    ws[OFF_M + ((v0 + vv) * P + p) * 2]     = dr;
                    ws[OFF_M + ((v0 + vv) * P + p) * 2 + 1] = di;
                }
            }
        }
    }
    gbar(flags + 0);

    // ================= P1: super-chunk scan (original k_scan), all 768 blocks
    // CHANGE vs atomic version: partial written to its own slot XP[b][p][sc].
    {
        float2* sM = (float2*)smem;              // V*192 float2 = 48KB exactly
        int x = bx % 24, b = bx / 24;
        int ph = x & 1;
        int sc = x >> 1;                          // [0,12)
        const float2* Mg = (const float2*)(ws + OFF_M);
        for (int f = tid; f < V * 192; f += 256) {
            int v = f / 192, i = f - v * 192;
            sM[f] = Mg[v * P + ph * 192 + i];
        }
        __syncthreads();
        if (tid < 192) {
            int p = ph * 192 + tid;
            float Lr = ws[OFF_LBF4 + 2 * p], Li = ws[OFF_LBF4 + 2 * p + 1];
            const int4* tkb = (const int4*)(tokens + b * L + sc * SCLEN);
            float ar0 = 0, ai0 = 0, ar1 = 0, ai1 = 0;
            float ar2 = 0, ai2 = 0, ar3 = 0, ai3 = 0;
            int4 tq = tkb[0];
            #pragma unroll 5
            for (int i = 0; i < NSTEP; ++i) {
                int4 cur = tq;
                if (i + 1 < NSTEP) tq = tkb[i + 1];
                float2 m0 = sM[cur.x * 192 + tid];
                float2 m1 = sM[cur.y * 192 + tid];
                float2 m2 = sM[cur.z * 192 + tid];
                float2 m3 = sM[cur.w * 192 + tid];
                float n;
                n = fmaf(Lr, ar0, fmaf(-Li, ai0, m0.x));
                ai0 = fmaf(Lr, ai0, fmaf(Li, ar0, m0.y)); ar0 = n;
                n = fmaf(Lr, ar1, fmaf(-Li, ai1, m1.x));
                ai1 = fmaf(Lr, ai1, fmaf(Li, ar1, m1.y)); ar1 = n;
                n = fmaf(Lr, ar2, fmaf(-Li, ai2, m2.x));
                ai2 = fmaf(Lr, ai2, fmaf(Li, ar2, m2.y)); ar2 = n;
                n = fmaf(Lr, ar3, fmaf(-Li, ai3, m3.x));
                ai3 = fmaf(Lr, ai3, fmaf(Li, ar3, m3.y)); ar3 = n;
            }
            const double* d = (const double*)ws + p * 6;
            double l1r = d[0], l1i = d[1];
            double l2r = l1r * l1r - l1i * l1i, l2i = 2.0 * l1r * l1i;
            double l3r = l2r * l1r - l2i * l1i, l3i = l2r * l1i + l2i * l1r;
            double zr = l3r * ar0 - l3i * ai0 + l2r * ar1 - l2i * ai1
                      + l1r * ar2 - l1i * ai2 + (double)ar3;
            double zi = l3r * ai0 + l3i * ar0 + l2r * ai1 + l2i * ar1
                      + l1r * ai2 + l1i * ar2 + (double)ai3;
            const double* wpow = (const double*)(ws + OFF_WPOW);
            double wr = wpow[(sc * P + p) * 2], wi = wpow[(sc * P + p) * 2 + 1];
            float sr = (float)(wr * zr - wi * zi);
            float si = (float)(wr * zi + wi * zr);
            float2* xp = (float2*)(ws + OFF_XP);
            xp[(b * P + p) * NSC + sc] = make_float2(sr, si);
        }
    }
    gbar(flags + 1);

    // ================= P2: x(T0) tail + y -> Yt (original k_y), 512 blocks
    if (bx < 512) {
        float* sxs  = (float*)smem;              // P*16 = 24KB
        float* sred = (float*)(smem + 24576);    // 4*64*9 = 9KB
        int b = bx >> 4, x = bx & 15;
        int lh = x & 1, hq = x >> 1;
        #pragma unroll
        for (int pass = 0; pass < 2; ++pass) {
            int p = tid + pass * 256;
            if (p < P) {
                const double* d = (const double*)ws + p * 6;
                double lbr = d[0], lbi = d[1], cr = d[4], ci = d[5];
                // sum the 12 slotted partials (deterministic, replaces atomics)
                const float2* xp = (const float2*)(ws + OFF_XP) + (b * P + p) * NSC;
                double zr = 0.0, zi = 0.0;
                #pragma unroll
                for (int s = 0; s < NSC; ++s) {
                    zr += (double)xp[s].x;
                    zi += (double)xp[s].y;
                }
                const float* M0 = ws + OFF_M;
                const int* tk = tokens + b * L + T0;
                #pragma unroll
                for (int j = 0; j < OUT_LEN; ++j) {
                    int t = tk[j];
                    double mr = (double)M0[(t * P + p) * 2];
                    double mi = (double)M0[(t * P + p) * 2 + 1];
                    double tr = lbr * zr - lbi * zi + mr;
                    double ti = lbr * zi + lbi * zr + mi;
                    zr = tr; zi = ti;
                    if ((j >> 3) == lh) {
                        int jl = j & 7;
                        sxs[p * 16 + 2 * jl]     = (float)(cr * zr - ci * zi);
                        sxs[p * 16 + 2 * jl + 1] = (float)(cr * zi + ci * zr);
                    }
                }
            }
        }
        __syncthreads();
        int hl = tid & 63, pg = tid >> 6;
        int h = hq * 64 + hl;
        const float* ct = ws + OFF_CT;
        float acc[8];
        #pragma unroll
        for (int i = 0; i < 8; ++i) acc[i] = 0.f;
        int p0 = pg * 96;
        float pr_[4], pi_[4];
        #pragma unroll
        for (int u = 0; u < 4; ++u) {
            pr_[u] = ct[(2 * (p0 + u)) * H + h];
            pi_[u] = ct[(2 * (p0 + u) + 1) * H + h];
        }
        for (int qs = 0; qs < 96; qs += 4) {
            float cr_[4], ci_[4];
            #pragma unroll
            for (int u = 0; u < 4; ++u) { cr_[u] = pr_[u]; ci_[u] = pi_[u]; }
            if (qs + 4 < 96) {
                #pragma unroll
                for (int u = 0; u < 4; ++u) {
                    pr_[u] = ct[(2 * (p0 + qs + 4 + u)) * H + h];
                    pi_[u] = ct[(2 * (p0 + qs + 4 + u) + 1) * H + h];
                }
            }
            #pragma unroll
            for (int u = 0; u < 4; ++u) {
                const float4* xv = (const float4*)(sxs + (p0 + qs + u) * 16);
                float4 x0 = xv[0], x1 = xv[1], x2 = xv[2], x3 = xv[3];
                float cre = cr_[u], cim = ci_[u];
                acc[0] = fmaf(cre, x0.x, fmaf(-cim, x0.y, acc[0]));
                acc[1] = fmaf(cre, x0.z, fmaf(-cim, x0.w, acc[1]));
                acc[2] = fmaf(cre, x1.x, fmaf(-cim, x1.y, acc[2]));
                acc[3] = fmaf(cre, x1.z, fmaf(-cim, x1.w, acc[3]));
                acc[4] = fmaf(cre, x2.x, fmaf(-cim, x2.y, acc[4]));
                acc[5] = fmaf(cre, x2.z, fmaf(-cim, x2.w, acc[5]));
                acc[6] = fmaf(cre, x3.x, fmaf(-cim, x3.y, acc[6]));
                acc[7] = fmaf(cre, x3.z, fmaf(-cim, x3.w, acc[7]));
            }
        }
        #pragma unroll
        for (int i = 0; i < 8; ++i)
            sred[(pg * 64 + hl) * 9 + i] = acc[i];
        __syncthreads();
        #pragma unroll
        for (int oo = 0; oo < 2; ++oo) {
            int o = tid + 256 * oo;
            int ohl = o & 63, oi = o >> 6;
            float s = sred[ohl * 9 + oi] + sred[(64 + ohl) * 9 + oi]
                    + sred[(128 + ohl) * 9 + oi] + sred[(192 + ohl) * 9 + oi];
            int l = lh * 8 + oi;
            int t = tokens[b * L + T0 + l];
            int hh = hq * 64 + ohl;
            ws[OFF_YT + (b * OUT_LEN + l) * H + hh] =
                2.f * s + embed[t * H + hh] * D[hh];
        }
    }
    gbar(flags + 2);

    // ================= P3: GEMM1 partials (original k_fc1), 512 blocks
    if (bx < 512) {
        float* ys = (float*)smem;                // 128*8 = 4KB
        float* hp = ws + OFF_HP;
        int rg = bx >> 3, jh = (bx >> 2) & 1, kc = bx & 3;
        int j = jh * 256 + tid;
        int r0 = rg * 8, k0 = kc * 128;
        const float* yt = ws + OFF_YT;
        int kk = tid & 127, rr = tid >> 7;
        #pragma unroll
        for (int it = 0; it < 4; ++it)
            ys[kk * 8 + rr + 2 * it] = yt[(r0 + rr + 2 * it) * H + k0 + kk];
        __syncthreads();
        const float* wp = W1 + k0 * H + j;
        float wreg[8];
        #pragma unroll
        for (int u = 0; u < 8; ++u) wreg[u] = wp[u * H];
        float acc[8] = {0, 0, 0, 0, 0, 0, 0, 0};
        for (int kb = 0; kb < 128; kb += 8) {
            float cur[8];
            #pragma unroll
            for (int u = 0; u < 8; ++u) cur[u] = wreg[u];
            if (kb + 8 < 128) {
                #pragma unroll
                for (int u = 0; u < 8; ++u) wreg[u] = wp[(kb + 8 + u) * H];
            }
            #pragma unroll
            for (int u = 0; u < 8; ++u) {
                const float4* y0 = (const float4*)(ys + (kb + u) * 8);
                float4 p0 = y0[0], p1 = y0[1];
                float a = cur[u];
                acc[0] = fmaf(p0.x, a, acc[0]);
                acc[1] = fmaf(p0.y, a, acc[1]);
                acc[2] = fmaf(p0.z, a, acc[2]);
                acc[3] = fmaf(p0.w, a, acc[3]);
                acc[4] = fmaf(p1.x, a, acc[4]);
                acc[5] = fmaf(p1.y, a, acc[5]);
                acc[6] = fmaf(p1.z, a, acc[6]);
                acc[7] = fmaf(p1.w, a, acc[7]);
            }
        }
        #pragma unroll
        for (int i = 0; i < 8; ++i)
            hp[(kc * 512 + r0 + i) * H + j] = acc[i];
    }
    gbar(flags + 3);

    // ================= P4: reduce + relu + GEMM2 (original k_fc2), 512 blocks
    if (bx < 512) {
        float* sh  = (float*)smem;               // 512 floats
        float* red = (float*)(smem + 2048);      // 8*32 floats
        const float* hp = ws + OFF_HP;
        int r = bx;
        #pragma unroll
        for (int half = 0; half < 2; ++half) {
            int j = half * 256 + tid;
            float s = b1[j] + hp[r * H + j] + hp[(512 + r) * H + j]
                            + hp[(1024 + r) * H + j] + hp[(1536 + r) * H + j];
            sh[j] = fmaxf(s, 0.f);
        }
        __syncthreads();
        int seg = tid >> 5, o = tid & 31;
        const float* w2 = W2 + seg * 64 * V + o;
        const float* hv = sh + seg * 64;
        float a0 = 0.f, a1 = 0.f, a2 = 0.f, a3 = 0.f;
        #pragma unroll
        for (int q = 0; q < 16; ++q) {
            a0 = fmaf(hv[q],      w2[q * V],        a0);
            a1 = fmaf(hv[16 + q], w2[(16 + q) * V], a1);
            a2 = fmaf(hv[32 + q], w2[(32 + q) * V], a2);
            a3 = fmaf(hv[48 + q], w2[(48 + q) * V], a3);
        }
        red[seg * 32 + o] = (a0 + a1) + (a2 + a3);
        __syncthreads();
        if (tid < 32) {
            float s = b2[tid];
            #pragma unroll
            for (int ss = 0; ss < 8; ++ss) s += red[ss * 32 + tid];
            out[r * V + tid] = s;
        }
    }
}

extern "C" void kernel_launch(void* const* d_in, const int* in_sizes, int n_in,
                              void* d_out, int out_size, void* d_ws, size_t ws_size,
                              hipStream_t stream)
{
    const int*   tokens = (const int*)d_in[0];
    const float* embed  = (const float*)d_in[1];
    const float* Lre    = (const float*)d_in[2];
    const float* Lim    = (const float*)d_in[3];
    const float* Bre    = (const float*)d_in[4];
    const float* Bim    = (const float*)d_in[5];
    const float* Cre    = (const float*)d_in[6];
    const float* Cim    = (const float*)d_in[7];
    const float* D      = (const float*)d_in[8];
    const float* lstep  = (const float*)d_in[9];
    const float* W1     = (const float*)d_in[10];
    const float* b1     = (const float*)d_in[11];
    const float* W2     = (const float*)d_in[12];
    const float* b2     = (const float*)d_in[13];
    float* out = (float*)d_out;
    float* ws  = (float*)d_ws;

    // zero only the 16 barrier-flag ints (scan partials are fully overwritten)
    hipMemsetAsync((void*)(ws + OFF_FLAGS), 0, 16 * sizeof(int), stream);

    k_all<<<dim3(NBLK), dim3(256), 0, stream>>>(
        tokens, embed, Lre, Lim, Bre, Bim, Cre, Cim,
        D, lstep, W1, b1, W2, b2, ws, out);
}

// Round 4
// 396.362 us; speedup vs baseline: 2.3896x; 2.3896x over previous
//
#include <hip/hip_runtime.h>

#define B_SZ 32
#define L 4096
#define H 512
#define P 384
#define V 32
#define OUT_LEN 16
#define NSC 12        // super-chunks
#define SCLEN 340     // 4 interleaved streams x 85 steps
#define NSTEP 85
#define T0 4080       // NSC*SCLEN; 16-step tail = the 16 output states

// ---- ws layout (float offsets) ----
#define OFF_DBL   0         // [P][6] doubles (lbr,lbi,-,-,cr,ci)
#define OFF_LBF4  4608      // [P][2] float Lambda_bar^4
#define OFF_WPOW  5376      // [NSC][P][2] doubles: W^(NSC-1-c), W = Lbar^340
#define OFF_M     23808     // [V][P][2] UNSCALED dot table M0
#define OFF_CT    48384     // [P][2][H] transposed C
#define OFF_XP    441600    // [B][P][NSC][2] slotted scan partials (no atomics)
#define OFF_FLAGS 736512    // 16 ints: grid-barrier counters (zeroed by memset)
#define OFF_YT    736528    // [512 r][512 h], r = b*16+l
#define OFF_HP    998672    // [4][512][512] fc1 k-split partials
// end = 2047248 floats = 8.2 MB

#define NBLK 768

// grid-wide barrier, ONE fence pair per BLOCK (not per wave — round-3's
// per-wave __threadfence() = ~24K buffer_wbl2/buffer_inv = 870us of L2-flush
// storms; and its ACQUIRE spin-load invalidated L2 every poll iteration).
// Correctness: __syncthreads() forces each wave's s_waitcnt vmcnt(0), so all
// waves' stores are in the XCD L2 before thread0 proceeds. The RELEASE RMW
// emits one buffer_wbl2 (whole-L2 writeback covers all waves' lines) before
// the add. Spin uses RELAXED agent loads (coherent sc0/sc1 access, NO cache
// invalidate per poll). After count==NBLK, every producer has flushed, so one
// ACQUIRE fence (buffer_inv: CU L1 + XCD L2) makes all fresh lines visible;
// __syncthreads() then releases the block's readers.
__device__ __forceinline__ void gbar(int* flag) {
    __syncthreads();   // all waves' stores drained to L2 (vmcnt 0 per wave)
    if (threadIdx.x == 0) {
        __hip_atomic_fetch_add(flag, 1, __ATOMIC_RELEASE,
                               __HIP_MEMORY_SCOPE_AGENT);     // wbl2 + add
        while (__hip_atomic_load(flag, __ATOMIC_RELAXED,
                                 __HIP_MEMORY_SCOPE_AGENT) < NBLK)
            __builtin_amdgcn_s_sleep(8);
        __builtin_amdgcn_fence(__ATOMIC_ACQUIRE, "agent");    // one buffer_inv
    }
    __syncthreads();
}

__global__ __launch_bounds__(256, 3) void k_all(
    const int* __restrict__ tokens, const float* __restrict__ embed,
    const float* __restrict__ Lre, const float* __restrict__ Lim,
    const float* __restrict__ Bre, const float* __restrict__ Bim,
    const float* __restrict__ Cre, const float* __restrict__ Cim,
    const float* __restrict__ D, const float* __restrict__ log_step,
    const float* __restrict__ W1, const float* __restrict__ b1,
    const float* __restrict__ W2, const float* __restrict__ b2,
    float* __restrict__ ws, float* __restrict__ out)
{
    __shared__ __align__(16) char smem[49152];   // 48KB, overlaid per phase
    int bx = blockIdx.x, tid = threadIdx.x;
    int* flags = (int*)(ws + OFF_FLAGS);

    // ================= P0: prep (original k_prep)
    if (bx < 2) {
        int p = bx * 256 + tid;
        if (p < P) {
            double dstep = exp((double)log_step[p]);
            double are = (double)Lre[p] * dstep, aim = (double)Lim[p] * dstep;
            double mag = exp(are);
            double lbr = mag * cos(aim), lbi = mag * sin(aim);
            double lre = (double)Lre[p], lim = (double)Lim[p];
            double nr = lbr - 1.0, ni = lbi;
            double den = lre * lre + lim * lim;
            double cr = (nr * lre + ni * lim) / den, ci = (ni * lre - nr * lim) / den;
            double* d = (double*)ws + p * 6;
            d[0] = lbr; d[1] = lbi; d[2] = 0.0; d[3] = 0.0; d[4] = cr; d[5] = ci;
            double m4 = exp(4.0 * are), a4 = 4.0 * aim;
            ws[OFF_LBF4 + 2 * p]     = (float)(m4 * cos(a4));
            ws[OFF_LBF4 + 2 * p + 1] = (float)(m4 * sin(a4));
            double wmag = exp((double)SCLEN * are);
            double wang = (double)SCLEN * aim;
            double wr = wmag * cos(wang), wi = wmag * sin(wang);
            double* wpow = (double*)(ws + OFF_WPOW);
            double awr = 1.0, awi = 0.0;
            for (int c = NSC - 1; c >= 0; --c) {
                wpow[(c * P + p) * 2]     = awr;
                wpow[(c * P + p) * 2 + 1] = awi;
                double t = awr * wr - awi * wi;
                awi = awr * wi + awi * wr;
                awr = t;
            }
        }
    } else if (bx < 194) {
        float (*sre)[33] = (float(*)[33])smem;
        float (*sim)[33] = (float(*)[33])(smem + 32 * 33 * 4);
        int bxx = bx - 2;
        int tp = bxx >> 4, th = bxx & 15;        // 12 p-tiles x 16 h-tiles
        int col = tid & 31, r0 = tid >> 5;
        #pragma unroll
        for (int it = 0; it < 4; ++it) {
            int row = r0 + 8 * it;
            int h = th * 32 + row, p = tp * 32 + col;
            sre[col][row] = Cre[h * P + p];
            sim[col][row] = Cim[h * P + p];
        }
        __syncthreads();
        #pragma unroll
        for (int it = 0; it < 4; ++it) {
            int pl = r0 + 8 * it;
            int p = tp * 32 + pl, h = th * 32 + col;
            ws[OFF_CT + (2 * p) * H + h]     = sre[pl][col];
            ws[OFF_CT + (2 * p + 1) * H + h] = sim[pl][col];
        }
    }
    if (bx < 384) {   // M0: 1536 wave-units
        int w = bx * 4 + (tid >> 6);
        if (w < 1536) {
            int v0 = (w & 3) * 8, p = w >> 2;
            int lane = tid & 63;
            const float4* brp = (const float4*)(Bre + p * H);
            const float4* bip = (const float4*)(Bim + p * H);
            float4 br0 = brp[lane], br1 = brp[lane + 64];
            float4 bi0 = bip[lane], bi1 = bip[lane + 64];
            #pragma unroll
            for (int vv = 0; vv < 8; ++vv) {
                const float4* evp = (const float4*)(embed + (v0 + vv) * H);
                float4 e0 = evp[lane], e1 = evp[lane + 64];
                float dr = br0.x * e0.x;
                dr = fmaf(br0.y, e0.y, dr); dr = fmaf(br0.z, e0.z, dr);
                dr = fmaf(br0.w, e0.w, dr); dr = fmaf(br1.x, e1.x, dr);
                dr = fmaf(br1.y, e1.y, dr); dr = fmaf(br1.z, e1.z, dr);
                dr = fmaf(br1.w, e1.w, dr);
                float di = bi0.x * e0.x;
                di = fmaf(bi0.y, e0.y, di); di = fmaf(bi0.z, e0.z, di);
                di = fmaf(bi0.w, e0.w, di); di = fmaf(bi1.x, e1.x, di);
                di = fmaf(bi1.y, e1.y, di); di = fmaf(bi1.z, e1.z, di);
                di = fmaf(bi1.w, e1.w, di);
                #pragma unroll
                for (int off = 32; off; off >>= 1) {
                    dr += __shfl_down(dr, off);
                    di += __shfl_down(di, off);
                }
                if (lane == 0) {
                    ws[OFF_M + ((v0 + vv) * P + p) * 2]     = dr;
                    ws[OFF_M + ((v0 + vv) * P + p) * 2 + 1] = di;
                }
            }
        }
    }
    gbar(flags + 0);

    // ================= P1: super-chunk scan (original k_scan), all 768 blocks
    {
        float2* sM = (float2*)smem;              // V*192 float2 = 48KB exactly
        int x = bx % 24, b = bx / 24;
        int ph = x & 1;
        int sc = x >> 1;                          // [0,12)
        const float2* Mg = (const float2*)(ws + OFF_M);
        for (int f = tid; f < V * 192; f += 256) {
            int v = f / 192, i = f - v * 192;
            sM[f] = Mg[v * P + ph * 192 + i];
        }
        __syncthreads();
        if (tid < 192) {
            int p = ph * 192 + tid;
            float Lr = ws[OFF_LBF4 + 2 * p], Li = ws[OFF_LBF4 + 2 * p + 1];
            const int4* tkb = (const int4*)(tokens + b * L + sc * SCLEN);
            float ar0 = 0, ai0 = 0, ar1 = 0, ai1 = 0;
            float ar2 = 0, ai2 = 0, ar3 = 0, ai3 = 0;
            int4 tq = tkb[0];
            #pragma unroll 5
            for (int i = 0; i < NSTEP; ++i) {
                int4 cur = tq;
                if (i + 1 < NSTEP) tq = tkb[i + 1];
                float2 m0 = sM[cur.x * 192 + tid];
                float2 m1 = sM[cur.y * 192 + tid];
                float2 m2 = sM[cur.z * 192 + tid];
                float2 m3 = sM[cur.w * 192 + tid];
                float n;
                n = fmaf(Lr, ar0, fmaf(-Li, ai0, m0.x));
                ai0 = fmaf(Lr, ai0, fmaf(Li, ar0, m0.y)); ar0 = n;
                n = fmaf(Lr, ar1, fmaf(-Li, ai1, m1.x));
                ai1 = fmaf(Lr, ai1, fmaf(Li, ar1, m1.y)); ar1 = n;
                n = fmaf(Lr, ar2, fmaf(-Li, ai2, m2.x));
                ai2 = fmaf(Lr, ai2, fmaf(Li, ar2, m2.y)); ar2 = n;
                n = fmaf(Lr, ar3, fmaf(-Li, ai3, m3.x));
                ai3 = fmaf(Lr, ai3, fmaf(Li, ar3, m3.y)); ar3 = n;
            }
            const double* d = (const double*)ws + p * 6;
            double l1r = d[0], l1i = d[1];
            double l2r = l1r * l1r - l1i * l1i, l2i = 2.0 * l1r * l1i;
            double l3r = l2r * l1r - l2i * l1i, l3i = l2r * l1i + l2i * l1r;
            double zr = l3r * ar0 - l3i * ai0 + l2r * ar1 - l2i * ai1
                      + l1r * ar2 - l1i * ai2 + (double)ar3;
            double zi = l3r * ai0 + l3i * ar0 + l2r * ai1 + l2i * ar1
                      + l1r * ai2 + l1i * ar2 + (double)ai3;
            const double* wpow = (const double*)(ws + OFF_WPOW);
            double wr = wpow[(sc * P + p) * 2], wi = wpow[(sc * P + p) * 2 + 1];
            float sr = (float)(wr * zr - wi * zi);
            float si = (float)(wr * zi + wi * zr);
            float2* xp = (float2*)(ws + OFF_XP);
            xp[(b * P + p) * NSC + sc] = make_float2(sr, si);
        }
    }
    gbar(flags + 1);

    // ================= P2: x(T0) tail + y -> Yt (original k_y), 512 blocks
    if (bx < 512) {
        float* sxs  = (float*)smem;              // P*16 = 24KB
        float* sred = (float*)(smem + 24576);    // 4*64*9 = 9KB
        int b = bx >> 4, x = bx & 15;
        int lh = x & 1, hq = x >> 1;
        #pragma unroll
        for (int pass = 0; pass < 2; ++pass) {
            int p = tid + pass * 256;
            if (p < P) {
                const double* d = (const double*)ws + p * 6;
                double lbr = d[0], lbi = d[1], cr = d[4], ci = d[5];
                const float2* xp = (const float2*)(ws + OFF_XP) + (b * P + p) * NSC;
                double zr = 0.0, zi = 0.0;
                #pragma unroll
                for (int s = 0; s < NSC; ++s) {
                    zr += (double)xp[s].x;
                    zi += (double)xp[s].y;
                }
                const float* M0 = ws + OFF_M;
                const int* tk = tokens + b * L + T0;
                #pragma unroll
                for (int j = 0; j < OUT_LEN; ++j) {
                    int t = tk[j];
                    double mr = (double)M0[(t * P + p) * 2];
                    double mi = (double)M0[(t * P + p) * 2 + 1];
                    double tr = lbr * zr - lbi * zi + mr;
                    double ti = lbr * zi + lbi * zr + mi;
                    zr = tr; zi = ti;
                    if ((j >> 3) == lh) {
                        int jl = j & 7;
                        sxs[p * 16 + 2 * jl]     = (float)(cr * zr - ci * zi);
                        sxs[p * 16 + 2 * jl + 1] = (float)(cr * zi + ci * zr);
                    }
                }
            }
        }
        __syncthreads();
        int hl = tid & 63, pg = tid >> 6;
        int h = hq * 64 + hl;
        const float* ct = ws + OFF_CT;
        float acc[8];
        #pragma unroll
        for (int i = 0; i < 8; ++i) acc[i] = 0.f;
        int p0 = pg * 96;
        float pr_[4], pi_[4];
        #pragma unroll
        for (int u = 0; u < 4; ++u) {
            pr_[u] = ct[(2 * (p0 + u)) * H + h];
            pi_[u] = ct[(2 * (p0 + u) + 1) * H + h];
        }
        for (int qs = 0; qs < 96; qs += 4) {
            float cr_[4], ci_[4];
            #pragma unroll
            for (int u = 0; u < 4; ++u) { cr_[u] = pr_[u]; ci_[u] = pi_[u]; }
            if (qs + 4 < 96) {
                #pragma unroll
                for (int u = 0; u < 4; ++u) {
                    pr_[u] = ct[(2 * (p0 + qs + 4 + u)) * H + h];
                    pi_[u] = ct[(2 * (p0 + qs + 4 + u) + 1) * H + h];
                }
            }
            #pragma unroll
            for (int u = 0; u < 4; ++u) {
                const float4* xv = (const float4*)(sxs + (p0 + qs + u) * 16);
                float4 x0 = xv[0], x1 = xv[1], x2 = xv[2], x3 = xv[3];
                float cre = cr_[u], cim = ci_[u];
                acc[0] = fmaf(cre, x0.x, fmaf(-cim, x0.y, acc[0]));
                acc[1] = fmaf(cre, x0.z, fmaf(-cim, x0.w, acc[1]));
                acc[2] = fmaf(cre, x1.x, fmaf(-cim, x1.y, acc[2]));
                acc[3] = fmaf(cre, x1.z, fmaf(-cim, x1.w, acc[3]));
                acc[4] = fmaf(cre, x2.x, fmaf(-cim, x2.y, acc[4]));
                acc[5] = fmaf(cre, x2.z, fmaf(-cim, x2.w, acc[5]));
                acc[6] = fmaf(cre, x3.x, fmaf(-cim, x3.y, acc[6]));
                acc[7] = fmaf(cre, x3.z, fmaf(-cim, x3.w, acc[7]));
            }
        }
        #pragma unroll
        for (int i = 0; i < 8; ++i)
            sred[(pg * 64 + hl) * 9 + i] = acc[i];
        __syncthreads();
        #pragma unroll
        for (int oo = 0; oo < 2; ++oo) {
            int o = tid + 256 * oo;
            int ohl = o & 63, oi = o >> 6;
            float s = sred[ohl * 9 + oi] + sred[(64 + ohl) * 9 + oi]
                    + sred[(128 + ohl) * 9 + oi] + sred[(192 + ohl) * 9 + oi];
            int l = lh * 8 + oi;
            int t = tokens[b * L + T0 + l];
            int hh = hq * 64 + ohl;
            ws[OFF_YT + (b * OUT_LEN + l) * H + hh] =
                2.f * s + embed[t * H + hh] * D[hh];
        }
    }
    gbar(flags + 2);

    // ================= P3: GEMM1 partials (original k_fc1), 512 blocks
    if (bx < 512) {
        float* ys = (float*)smem;                // 128*8 = 4KB
        float* hp = ws + OFF_HP;
        int rg = bx >> 3, jh = (bx >> 2) & 1, kc = bx & 3;
        int j = jh * 256 + tid;
        int r0 = rg * 8, k0 = kc * 128;
        const float* yt = ws + OFF_YT;
        int kk = tid & 127, rr = tid >> 7;
        #pragma unroll
        for (int it = 0; it < 4; ++it)
            ys[kk * 8 + rr + 2 * it] = yt[(r0 + rr + 2 * it) * H + k0 + kk];
        __syncthreads();
        const float* wp = W1 + k0 * H + j;
        float wreg[8];
        #pragma unroll
        for (int u = 0; u < 8; ++u) wreg[u] = wp[u * H];
        float acc[8] = {0, 0, 0, 0, 0, 0, 0, 0};
        for (int kb = 0; kb < 128; kb += 8) {
            float cur[8];
            #pragma unroll
            for (int u = 0; u < 8; ++u) cur[u] = wreg[u];
            if (kb + 8 < 128) {
                #pragma unroll
                for (int u = 0; u < 8; ++u) wreg[u] = wp[(kb + 8 + u) * H];
            }
            #pragma unroll
            for (int u = 0; u < 8; ++u) {
                const float4* y0 = (const float4*)(ys + (kb + u) * 8);
                float4 p0 = y0[0], p1 = y0[1];
                float a = cur[u];
                acc[0] = fmaf(p0.x, a, acc[0]);
                acc[1] = fmaf(p0.y, a, acc[1]);
                acc[2] = fmaf(p0.z, a, acc[2]);
                acc[3] = fmaf(p0.w, a, acc[3]);
                acc[4] = fmaf(p1.x, a, acc[4]);
                acc[5] = fmaf(p1.y, a, acc[5]);
                acc[6] = fmaf(p1.z, a, acc[6]);
                acc[7] = fmaf(p1.w, a, acc[7]);
            }
        }
        #pragma unroll
        for (int i = 0; i < 8; ++i)
            hp[(kc * 512 + r0 + i) * H + j] = acc[i];
    }
    gbar(flags + 3);

    // ================= P4: reduce + relu + GEMM2 (original k_fc2), 512 blocks
    if (bx < 512) {
        float* sh  = (float*)smem;               // 512 floats
        float* red = (float*)(smem + 2048);      // 8*32 floats
        const float* hp = ws + OFF_HP;
        int r = bx;
        #pragma unroll
        for (int half = 0; half < 2; ++half) {
            int j = half * 256 + tid;
            float s = b1[j] + hp[r * H + j] + hp[(512 + r) * H + j]
                            + hp[(1024 + r) * H + j] + hp[(1536 + r) * H + j];
            sh[j] = fmaxf(s, 0.f);
        }
        __syncthreads();
        int seg = tid >> 5, o = tid & 31;
        const float* w2 = W2 + seg * 64 * V + o;
        const float* hv = sh + seg * 64;
        float a0 = 0.f, a1 = 0.f, a2 = 0.f, a3 = 0.f;
        #pragma unroll
        for (int q = 0; q < 16; ++q) {
            a0 = fmaf(hv[q],      w2[q * V],        a0);
            a1 = fmaf(hv[16 + q], w2[(16 + q) * V], a1);
            a2 = fmaf(hv[32 + q], w2[(32 + q) * V], a2);
            a3 = fmaf(hv[48 + q], w2[(48 + q) * V], a3);
        }
        red[seg * 32 + o] = (a0 + a1) + (a2 + a3);
        __syncthreads();
        if (tid < 32) {
            float s = b2[tid];
            #pragma unroll
            for (int ss = 0; ss < 8; ++ss) s += red[ss * 32 + tid];
            out[r * V + tid] = s;
        }
    }
}

extern "C" void kernel_launch(void* const* d_in, const int* in_sizes, int n_in,
                              void* d_out, int out_size, void* d_ws, size_t ws_size,
                              hipStream_t stream)
{
    const int*   tokens = (const int*)d_in[0];
    const float* embed  = (const float*)d_in[1];
    const float* Lre    = (const float*)d_in[2];
    const float* Lim    = (const float*)d_in[3];
    const float* Bre    = (const float*)d_in[4];
    const float* Bim    = (const float*)d_in[5];
    const float* Cre    = (const float*)d_in[6];
    const float* Cim    = (const float*)d_in[7];
    const float* D      = (const float*)d_in[8];
    const float* lstep  = (const float*)d_in[9];
    const float* W1     = (const float*)d_in[10];
    const float* b1     = (const float*)d_in[11];
    const float* W2     = (const float*)d_in[12];
    const float* b2     = (const float*)d_in[13];
    float* out = (float*)d_out;
    float* ws  = (float*)d_ws;

    // zero only the 16 barrier-flag ints (scan partials are fully overwritten)
    hipMemsetAsync((void*)(ws + OFF_FLAGS), 0, 16 * sizeof(int), stream);

    k_all<<<dim3(NBLK), dim3(256), 0, stream>>>(
        tokens, embed, Lre, Lim, Bre, Bim, Cre, Cim,
        D, lstep, W1, b1, W2, b2, ws, out);
}

// Round 5
// 153.264 us; speedup vs baseline: 6.1798x; 2.5861x over previous
//
#include <hip/hip_runtime.h>

#define B_SZ 32
#define L 4096
#define H 512
#define P 384
#define V 32
#define OUT_LEN 16
#define NSC 12        // super-chunks
#define SCLEN 340     // 4 interleaved streams x 85 steps
#define NSTEP 85
#define T0 4080       // NSC*SCLEN; 16-step tail = the 16 output states

// ---- ws layout (float offsets) ----
#define OFF_DBL   0         // [P][6] doubles (lbr,lbi,-,-,cr,ci)
#define OFF_LBF4  4608      // [P][2] float Lambda_bar^4
#define OFF_WPOW  5376      // [NSC][P][2] doubles: W^(NSC-1-c), W = Lbar^340
#define OFF_M     23808     // [V][P][2] UNSCALED dot table M0
#define OFF_CT    48384     // [P][2][H] transposed C
#define OFF_XP    441600    // [B][P][NSC][2] slotted scan partials (no atomics)
#define OFF_FLAGS 736512    // 2560 ints: census/arrive/done/inv (memset to 0)
#define OFF_YT    739072    // [512 r][512 h], r = b*16+l
#define OFF_HP    1001216   // [4][512][512] fc1 k-split partials
// end = 2049792 floats = 8.2 MB

#define NBLK 768
#define NXCD 8

// flags layout (int offsets inside flags region; counters padded to 128B)
#define FCEN(x)      ((x) * 32)                       // [0,256)
#define FARR(ph, x)  (256 + (ph) * 512 + (x) * 32)    // [256,2304)
#define FDONE(ph)    (2304 + (ph) * 32)               // [2304,2432)
#define FINV(ph)     (2432 + (ph) * 32)               // [2432,2560)

__device__ __forceinline__ int xcc_id() {
    int x;
    asm volatile("s_getreg_b32 %0, hwreg(HW_REG_XCC_ID)" : "=s"(x));
    return x & (NXCD - 1);
}

// Hierarchical grid barrier: cache maintenance ONCE PER XCD, not per block.
// Round-4's per-block release-RMW/acquire-fence = 768 buffer_wbl2 + 768
// buffer_inv per barrier; ~96 full-L2 scans serialize at each L2 -> ~74us
// per barrier (measured: 324us kernel, 5.8% VALUBusy). The HW only needs one
// wbl2 + one inv per XCD L2 per barrier.
//  - arrive: after __syncthreads (emits s_waitcnt vmcnt(0): all the block's
//    stores are acked by its XCD L2), relaxed agent RMW on per-XCD counter.
//  - XCD leader (census first-arriver): waits its XCD complete, ONE release
//    fence (wbl2: whole-L2 writeback covers all resident blocks' lines),
//    bumps done; waits done==8 (all XCDs' data in L3), ONE acquire fence
//    (inv: L1+L2), bumps inv.
//  - everyone: waits inv==8 via relaxed agent loads (no cache ops per poll).
// L1 staleness is safe: every cross-phase buffer is write-once-then-read and
// stores don't allocate L1 (validated by round-4 passing with same property).
__device__ __forceinline__ void gbar(int* F, int ph, int xcd, int leader) {
    __syncthreads();   // all waves' stores drained to this XCD's L2
    if (threadIdx.x == 0) {
        __hip_atomic_fetch_add(&F[FARR(ph, xcd)], 1, __ATOMIC_RELAXED,
                               __HIP_MEMORY_SCOPE_AGENT);
        if (leader) {
            if (ph == 0) {  // close the census race: all blocks census'd
                for (;;) {
                    int tot = 0;
                    for (int x2 = 0; x2 < NXCD; ++x2)
                        tot += __hip_atomic_load(&F[FCEN(x2)], __ATOMIC_RELAXED,
                                                 __HIP_MEMORY_SCOPE_AGENT);
                    if (tot >= NBLK) break;
                    __builtin_amdgcn_s_sleep(2);
                }
            }
            for (;;) {      // wait: every resident block on my XCD arrived
                int a = __hip_atomic_load(&F[FARR(ph, xcd)], __ATOMIC_RELAXED,
                                          __HIP_MEMORY_SCOPE_AGENT);
                int c = __hip_atomic_load(&F[FCEN(xcd)], __ATOMIC_RELAXED,
                                          __HIP_MEMORY_SCOPE_AGENT);
                if (a >= c) break;
                __builtin_amdgcn_s_sleep(2);
            }
            __builtin_amdgcn_fence(__ATOMIC_RELEASE, "agent");   // 1 wbl2/XCD
            __hip_atomic_fetch_add(&F[FDONE(ph)], 1, __ATOMIC_RELAXED,
                                   __HIP_MEMORY_SCOPE_AGENT);
            while (__hip_atomic_load(&F[FDONE(ph)], __ATOMIC_RELAXED,
                                     __HIP_MEMORY_SCOPE_AGENT) < NXCD)
                __builtin_amdgcn_s_sleep(2);
            __builtin_amdgcn_fence(__ATOMIC_ACQUIRE, "agent");   // 1 inv/XCD
            __hip_atomic_fetch_add(&F[FINV(ph)], 1, __ATOMIC_RELAXED,
                                   __HIP_MEMORY_SCOPE_AGENT);
        }
        while (__hip_atomic_load(&F[FINV(ph)], __ATOMIC_RELAXED,
                                 __HIP_MEMORY_SCOPE_AGENT) < NXCD)
            __builtin_amdgcn_s_sleep(8);
    }
    __syncthreads();
}

__global__ __launch_bounds__(256, 3) void k_all(
    const int* __restrict__ tokens, const float* __restrict__ embed,
    const float* __restrict__ Lre, const float* __restrict__ Lim,
    const float* __restrict__ Bre, const float* __restrict__ Bim,
    const float* __restrict__ Cre, const float* __restrict__ Cim,
    const float* __restrict__ D, const float* __restrict__ log_step,
    const float* __restrict__ W1, const float* __restrict__ b1,
    const float* __restrict__ W2, const float* __restrict__ b2,
    float* __restrict__ ws, float* __restrict__ out)
{
    __shared__ __align__(16) char smem[49152];   // 48KB, overlaid per phase
    int bx = blockIdx.x, tid = threadIdx.x;
    int* flags = (int*)(ws + OFF_FLAGS);

    // census: elect one leader block per physical XCD (first arriver)
    int xcd = xcc_id();
    int leader = 0;
    if (tid == 0) {
        int ord = __hip_atomic_fetch_add(&flags[FCEN(xcd)], 1, __ATOMIC_RELAXED,
                                         __HIP_MEMORY_SCOPE_AGENT);
        leader = (ord == 0);
    }

    // ================= P0: prep (original k_prep)
    if (bx < 2) {
        int p = bx * 256 + tid;
        if (p < P) {
            double dstep = exp((double)log_step[p]);
            double are = (double)Lre[p] * dstep, aim = (double)Lim[p] * dstep;
            double mag = exp(are);
            double lbr = mag * cos(aim), lbi = mag * sin(aim);
            double lre = (double)Lre[p], lim = (double)Lim[p];
            double nr = lbr - 1.0, ni = lbi;
            double den = lre * lre + lim * lim;
            double cr = (nr * lre + ni * lim) / den, ci = (ni * lre - nr * lim) / den;
            double* d = (double*)ws + p * 6;
            d[0] = lbr; d[1] = lbi; d[2] = 0.0; d[3] = 0.0; d[4] = cr; d[5] = ci;
            double m4 = exp(4.0 * are), a4 = 4.0 * aim;
            ws[OFF_LBF4 + 2 * p]     = (float)(m4 * cos(a4));
            ws[OFF_LBF4 + 2 * p + 1] = (float)(m4 * sin(a4));
            double wmag = exp((double)SCLEN * are);
            double wang = (double)SCLEN * aim;
            double wr = wmag * cos(wang), wi = wmag * sin(wang);
            double* wpow = (double*)(ws + OFF_WPOW);
            double awr = 1.0, awi = 0.0;
            for (int c = NSC - 1; c >= 0; --c) {
                wpow[(c * P + p) * 2]     = awr;
                wpow[(c * P + p) * 2 + 1] = awi;
                double t = awr * wr - awi * wi;
                awi = awr * wi + awi * wr;
                awr = t;
            }
        }
    } else if (bx < 194) {
        float (*sre)[33] = (float(*)[33])smem;
        float (*sim)[33] = (float(*)[33])(smem + 32 * 33 * 4);
        int bxx = bx - 2;
        int tp = bxx >> 4, th = bxx & 15;        // 12 p-tiles x 16 h-tiles
        int col = tid & 31, r0 = tid >> 5;
        #pragma unroll
        for (int it = 0; it < 4; ++it) {
            int row = r0 + 8 * it;
            int h = th * 32 + row, p = tp * 32 + col;
            sre[col][row] = Cre[h * P + p];
            sim[col][row] = Cim[h * P + p];
        }
        __syncthreads();
        #pragma unroll
        for (int it = 0; it < 4; ++it) {
            int pl = r0 + 8 * it;
            int p = tp * 32 + pl, h = th * 32 + col;
            ws[OFF_CT + (2 * p) * H + h]     = sre[pl][col];
            ws[OFF_CT + (2 * p + 1) * H + h] = sim[pl][col];
        }
    }
    if (bx < 384) {   // M0: 1536 wave-units
        int w = bx * 4 + (tid >> 6);
        if (w < 1536) {
            int v0 = (w & 3) * 8, p = w >> 2;
            int lane = tid & 63;
            const float4* brp = (const float4*)(Bre + p * H);
            const float4* bip = (const float4*)(Bim + p * H);
            float4 br0 = brp[lane], br1 = brp[lane + 64];
            float4 bi0 = bip[lane], bi1 = bip[lane + 64];
            #pragma unroll
            for (int vv = 0; vv < 8; ++vv) {
                const float4* evp = (const float4*)(embed + (v0 + vv) * H);
                float4 e0 = evp[lane], e1 = evp[lane + 64];
                float dr = br0.x * e0.x;
                dr = fmaf(br0.y, e0.y, dr); dr = fmaf(br0.z, e0.z, dr);
                dr = fmaf(br0.w, e0.w, dr); dr = fmaf(br1.x, e1.x, dr);
                dr = fmaf(br1.y, e1.y, dr); dr = fmaf(br1.z, e1.z, dr);
                dr = fmaf(br1.w, e1.w, dr);
                float di = bi0.x * e0.x;
                di = fmaf(bi0.y, e0.y, di); di = fmaf(bi0.z, e0.z, di);
                di = fmaf(bi0.w, e0.w, di); di = fmaf(bi1.x, e1.x, di);
                di = fmaf(bi1.y, e1.y, di); di = fmaf(bi1.z, e1.z, di);
                di = fmaf(bi1.w, e1.w, di);
                #pragma unroll
                for (int off = 32; off; off >>= 1) {
                    dr += __shfl_down(dr, off);
                    di += __shfl_down(di, off);
                }
                if (lane == 0) {
                    ws[OFF_M + ((v0 + vv) * P + p) * 2]     = dr;
                    ws[OFF_M + ((v0 + vv) * P + p) * 2 + 1] = di;
                }
            }
        }
    }
    gbar(flags, 0, xcd, leader);

    // ================= P1: super-chunk scan (original k_scan), all 768 blocks
    {
        float2* sM = (float2*)smem;              // V*192 float2 = 48KB exactly
        int x = bx % 24, b = bx / 24;
        int ph = x & 1;
        int sc = x >> 1;                          // [0,12)
        const float2* Mg = (const float2*)(ws + OFF_M);
        for (int f = tid; f < V * 192; f += 256) {
            int v = f / 192, i = f - v * 192;
            sM[f] = Mg[v * P + ph * 192 + i];
        }
        __syncthreads();
        if (tid < 192) {
            int p = ph * 192 + tid;
            float Lr = ws[OFF_LBF4 + 2 * p], Li = ws[OFF_LBF4 + 2 * p + 1];
            const int4* tkb = (const int4*)(tokens + b * L + sc * SCLEN);
            float ar0 = 0, ai0 = 0, ar1 = 0, ai1 = 0;
            float ar2 = 0, ai2 = 0, ar3 = 0, ai3 = 0;
            int4 tq = tkb[0];
            #pragma unroll 5
            for (int i = 0; i < NSTEP; ++i) {
                int4 cur = tq;
                if (i + 1 < NSTEP) tq = tkb[i + 1];
                float2 m0 = sM[cur.x * 192 + tid];
                float2 m1 = sM[cur.y * 192 + tid];
                float2 m2 = sM[cur.z * 192 + tid];
                float2 m3 = sM[cur.w * 192 + tid];
                float n;
                n = fmaf(Lr, ar0, fmaf(-Li, ai0, m0.x));
                ai0 = fmaf(Lr, ai0, fmaf(Li, ar0, m0.y)); ar0 = n;
                n = fmaf(Lr, ar1, fmaf(-Li, ai1, m1.x));
                ai1 = fmaf(Lr, ai1, fmaf(Li, ar1, m1.y)); ar1 = n;
                n = fmaf(Lr, ar2, fmaf(-Li, ai2, m2.x));
                ai2 = fmaf(Lr, ai2, fmaf(Li, ar2, m2.y)); ar2 = n;
                n = fmaf(Lr, ar3, fmaf(-Li, ai3, m3.x));
                ai3 = fmaf(Lr, ai3, fmaf(Li, ar3, m3.y)); ar3 = n;
            }
            const double* d = (const double*)ws + p * 6;
            double l1r = d[0], l1i = d[1];
            double l2r = l1r * l1r - l1i * l1i, l2i = 2.0 * l1r * l1i;
            double l3r = l2r * l1r - l2i * l1i, l3i = l2r * l1i + l2i * l1r;
            double zr = l3r * ar0 - l3i * ai0 + l2r * ar1 - l2i * ai1
                      + l1r * ar2 - l1i * ai2 + (double)ar3;
            double zi = l3r * ai0 + l3i * ar0 + l2r * ai1 + l2i * ar1
                      + l1r * ai2 + l1i * ar2 + (double)ai3;
            const double* wpow = (const double*)(ws + OFF_WPOW);
            double wr = wpow[(sc * P + p) * 2], wi = wpow[(sc * P + p) * 2 + 1];
            float sr = (float)(wr * zr - wi * zi);
            float si = (float)(wr * zi + wi * zr);
            float2* xp = (float2*)(ws + OFF_XP);
            xp[(b * P + p) * NSC + sc] = make_float2(sr, si);
        }
    }
    gbar(flags, 1, xcd, leader);

    // ================= P2: x(T0) tail + y -> Yt (original k_y), 512 blocks
    if (bx < 512) {
        float* sxs  = (float*)smem;              // P*16 = 24KB
        float* sred = (float*)(smem + 24576);    // 4*64*9 = 9KB
        int b = bx >> 4, x = bx & 15;
        int lh = x & 1, hq = x >> 1;
        #pragma unroll
        for (int pass = 0; pass < 2; ++pass) {
            int p = tid + pass * 256;
            if (p < P) {
                const double* d = (const double*)ws + p * 6;
                double lbr = d[0], lbi = d[1], cr = d[4], ci = d[5];
                const float2* xp = (const float2*)(ws + OFF_XP) + (b * P + p) * NSC;
                double zr = 0.0, zi = 0.0;
                #pragma unroll
                for (int s = 0; s < NSC; ++s) {
                    zr += (double)xp[s].x;
                    zi += (double)xp[s].y;
                }
                const float* M0 = ws + OFF_M;
                const int* tk = tokens + b * L + T0;
                #pragma unroll
                for (int j = 0; j < OUT_LEN; ++j) {
                    int t = tk[j];
                    double mr = (double)M0[(t * P + p) * 2];
                    double mi = (double)M0[(t * P + p) * 2 + 1];
                    double tr = lbr * zr - lbi * zi + mr;
                    double ti = lbr * zi + lbi * zr + mi;
                    zr = tr; zi = ti;
                    if ((j >> 3) == lh) {
                        int jl = j & 7;
                        sxs[p * 16 + 2 * jl]     = (float)(cr * zr - ci * zi);
                        sxs[p * 16 + 2 * jl + 1] = (float)(cr * zi + ci * zr);
                    }
                }
            }
        }
        __syncthreads();
        int hl = tid & 63, pg = tid >> 6;
        int h = hq * 64 + hl;
        const float* ct = ws + OFF_CT;
        float acc[8];
        #pragma unroll
        for (int i = 0; i < 8; ++i) acc[i] = 0.f;
        int p0 = pg * 96;
        float pr_[4], pi_[4];
        #pragma unroll
        for (int u = 0; u < 4; ++u) {
            pr_[u] = ct[(2 * (p0 + u)) * H + h];
            pi_[u] = ct[(2 * (p0 + u) + 1) * H + h];
        }
        for (int qs = 0; qs < 96; qs += 4) {
            float cr_[4], ci_[4];
            #pragma unroll
            for (int u = 0; u < 4; ++u) { cr_[u] = pr_[u]; ci_[u] = pi_[u]; }
            if (qs + 4 < 96) {
                #pragma unroll
                for (int u = 0; u < 4; ++u) {
                    pr_[u] = ct[(2 * (p0 + qs + 4 + u)) * H + h];
                    pi_[u] = ct[(2 * (p0 + qs + 4 + u) + 1) * H + h];
                }
            }
            #pragma unroll
            for (int u = 0; u < 4; ++u) {
                const float4* xv = (const float4*)(sxs + (p0 + qs + u) * 16);
                float4 x0 = xv[0], x1 = xv[1], x2 = xv[2], x3 = xv[3];
                float cre = cr_[u], cim = ci_[u];
                acc[0] = fmaf(cre, x0.x, fmaf(-cim, x0.y, acc[0]));
                acc[1] = fmaf(cre, x0.z, fmaf(-cim, x0.w, acc[1]));
                acc[2] = fmaf(cre, x1.x, fmaf(-cim, x1.y, acc[2]));
                acc[3] = fmaf(cre, x1.z, fmaf(-cim, x1.w, acc[3]));
                acc[4] = fmaf(cre, x2.x, fmaf(-cim, x2.y, acc[4]));
                acc[5] = fmaf(cre, x2.z, fmaf(-cim, x2.w, acc[5]));
                acc[6] = fmaf(cre, x3.x, fmaf(-cim, x3.y, acc[6]));
                acc[7] = fmaf(cre, x3.z, fmaf(-cim, x3.w, acc[7]));
            }
        }
        #pragma unroll
        for (int i = 0; i < 8; ++i)
            sred[(pg * 64 + hl) * 9 + i] = acc[i];
        __syncthreads();
        #pragma unroll
        for (int oo = 0; oo < 2; ++oo) {
            int o = tid + 256 * oo;
            int ohl = o & 63, oi = o >> 6;
            float s = sred[ohl * 9 + oi] + sred[(64 + ohl) * 9 + oi]
                    + sred[(128 + ohl) * 9 + oi] + sred[(192 + ohl) * 9 + oi];
            int l = lh * 8 + oi;
            int t = tokens[b * L + T0 + l];
            int hh = hq * 64 + ohl;
            ws[OFF_YT + (b * OUT_LEN + l) * H + hh] =
                2.f * s + embed[t * H + hh] * D[hh];
        }
    }
    gbar(flags, 2, xcd, leader);

    // ================= P3: GEMM1 partials (original k_fc1), 512 blocks
    if (bx < 512) {
        float* ys = (float*)smem;                // 128*8 = 4KB
        float* hp = ws + OFF_HP;
        int rg = bx >> 3, jh = (bx >> 2) & 1, kc = bx & 3;
        int j = jh * 256 + tid;
        int r0 = rg * 8, k0 = kc * 128;
        const float* yt = ws + OFF_YT;
        int kk = tid & 127, rr = tid >> 7;
        #pragma unroll
        for (int it = 0; it < 4; ++it)
            ys[kk * 8 + rr + 2 * it] = yt[(r0 + rr + 2 * it) * H + k0 + kk];
        __syncthreads();
        const float* wp = W1 + k0 * H + j;
        float wreg[8];
        #pragma unroll
        for (int u = 0; u < 8; ++u) wreg[u] = wp[u * H];
        float acc[8] = {0, 0, 0, 0, 0, 0, 0, 0};
        for (int kb = 0; kb < 128; kb += 8) {
            float cur[8];
            #pragma unroll
            for (int u = 0; u < 8; ++u) cur[u] = wreg[u];
            if (kb + 8 < 128) {
                #pragma unroll
                for (int u = 0; u < 8; ++u) wreg[u] = wp[(kb + 8 + u) * H];
            }
            #pragma unroll
            for (int u = 0; u < 8; ++u) {
                const float4* y0 = (const float4*)(ys + (kb + u) * 8);
                float4 p0 = y0[0], p1 = y0[1];
                float a = cur[u];
                acc[0] = fmaf(p0.x, a, acc[0]);
                acc[1] = fmaf(p0.y, a, acc[1]);
                acc[2] = fmaf(p0.z, a, acc[2]);
                acc[3] = fmaf(p0.w, a, acc[3]);
                acc[4] = fmaf(p1.x, a, acc[4]);
                acc[5] = fmaf(p1.y, a, acc[5]);
                acc[6] = fmaf(p1.z, a, acc[6]);
                acc[7] = fmaf(p1.w, a, acc[7]);
            }
        }
        #pragma unroll
        for (int i = 0; i < 8; ++i)
            hp[(kc * 512 + r0 + i) * H + j] = acc[i];
    }
    gbar(flags, 3, xcd, leader);

    // ================= P4: reduce + relu + GEMM2 (original k_fc2), 512 blocks
    if (bx < 512) {
        float* sh  = (float*)smem;               // 512 floats
        float* red = (float*)(smem + 2048);      // 8*32 floats
        const float* hp = ws + OFF_HP;
        int r = bx;
        #pragma unroll
        for (int half = 0; half < 2; ++half) {
            int j = half * 256 + tid;
            float s = b1[j] + hp[r * H + j] + hp[(512 + r) * H + j]
                            + hp[(1024 + r) * H + j] + hp[(1536 + r) * H + j];
            sh[j] = fmaxf(s, 0.f);
        }
        __syncthreads();
        int seg = tid >> 5, o = tid & 31;
        const float* w2 = W2 + seg * 64 * V + o;
        const float* hv = sh + seg * 64;
        float a0 = 0.f, a1 = 0.f, a2 = 0.f, a3 = 0.f;
        #pragma unroll
        for (int q = 0; q < 16; ++q) {
            a0 = fmaf(hv[q],      w2[q * V],        a0);
            a1 = fmaf(hv[16 + q], w2[(16 + q) * V], a1);
            a2 = fmaf(hv[32 + q], w2[(32 + q) * V], a2);
            a3 = fmaf(hv[48 + q], w2[(48 + q) * V], a3);
        }
        red[seg * 32 + o] = (a0 + a1) + (a2 + a3);
        __syncthreads();
        if (tid < 32) {
            float s = b2[tid];
            #pragma unroll
            for (int ss = 0; ss < 8; ++ss) s += red[ss * 32 + tid];
            out[r * V + tid] = s;
        }
    }
}

extern "C" void kernel_launch(void* const* d_in, const int* in_sizes, int n_in,
                              void* d_out, int out_size, void* d_ws, size_t ws_size,
                              hipStream_t stream)
{
    const int*   tokens = (const int*)d_in[0];
    const float* embed  = (const float*)d_in[1];
    const float* Lre    = (const float*)d_in[2];
    const float* Lim    = (const float*)d_in[3];
    const float* Bre    = (const float*)d_in[4];
    const float* Bim    = (const float*)d_in[5];
    const float* Cre    = (const float*)d_in[6];
    const float* Cim    = (const float*)d_in[7];
    const float* D      = (const float*)d_in[8];
    const float* lstep  = (const float*)d_in[9];
    const float* W1     = (const float*)d_in[10];
    const float* b1     = (const float*)d_in[11];
    const float* W2     = (const float*)d_in[12];
    const float* b2     = (const float*)d_in[13];
    float* out = (float*)d_out;
    float* ws  = (float*)d_ws;

    // zero the 2560 barrier-flag ints (10 KB)
    hipMemsetAsync((void*)(ws + OFF_FLAGS), 0, 2560 * sizeof(int), stream);

    k_all<<<dim3(NBLK), dim3(256), 0, stream>>>(
        tokens, embed, Lre, Lim, Bre, Bim, Cre, Cim,
        D, lstep, W1, b1, W2, b2, ws, out);
}